// Round 8
// baseline (511.360 us; speedup 1.0000x reference)
//
#include <hip/hip_runtime.h>

#define Bv 64
#define Tv 2048
#define Hv 1024
#define Uv 128
#define Mv 512

typedef __bf16 bf16x8 __attribute__((ext_vector_type(8)));
typedef float f32x4 __attribute__((ext_vector_type(4)));

union U4BF { uint4 u; bf16x8 b; };

#define MFMA(a, b, c) __builtin_amdgcn_mfma_f32_16x16x32_bf16((a), (b), (c), 0, 0, 0)

// async global->LDS, 16B per lane, dest = wave-uniform base + lane*16
#define GLOAD_LDS16(g, l) __builtin_amdgcn_global_load_lds( \
    (const __attribute__((address_space(1))) unsigned int*)(g), \
    (__attribute__((address_space(3))) unsigned int*)(l), 16, 0, 0)

__device__ __forceinline__ unsigned short f2bf(float f) {
  __bf16 h = (__bf16)f;
  return __builtin_bit_cast(unsigned short, h);
}
__device__ __forceinline__ unsigned int pack2(unsigned short lo, unsigned short hi) {
  return (unsigned int)lo | ((unsigned int)hi << 16);
}
// fast tanh/sigmoid via v_exp (saturates correctly at +/-inf)
__device__ __forceinline__ float tanh_fast(float x) {
  float e = __expf(2.0f * x);
  return 1.0f - 2.0f / (e + 1.0f);
}
__device__ __forceinline__ float sigmoid_fast(float x) {
  return 1.0f / (1.0f + __expf(-x));
}

// ---------------- kPre: pq + P0/P1/Ssg zero (bx<64) | W2->w3tmp->W3F (bx==64) | WmF/WeF pack (bx>=65) ----------------
__global__ __launch_bounds__(256) void kpre_kernel(
    const float* __restrict__ query, const float* __restrict__ Wq,
    const float* __restrict__ bq, const float* __restrict__ Wl,
    const float* __restrict__ bl, const float* __restrict__ conv_w,
    const float* __restrict__ conv_b, const float* __restrict__ Wm,
    const float* __restrict__ We,
    float* __restrict__ pq, float* __restrict__ bias2,
    unsigned short* __restrict__ WmF, unsigned short* __restrict__ WeF,
    unsigned short* __restrict__ W3F,
    float* __restrict__ P0, float* __restrict__ P1, float* __restrict__ Ssg) {
  const int bx = blockIdx.x, tid = threadIdx.x;

  if (bx < 64) {
    // pq[b,:] = query[b]@Wq + bq (split h-range over 2 halves), plus zeroing
    __shared__ float sTmp[2][128];
    const int b = bx;
    const int u = tid & 127, half = tid >> 7;
    float acc = 0.0f;
    const float* q  = query + b * Hv + half * 512;
    const float* wq = Wq + (size_t)half * 512 * Uv + u;
    #pragma unroll 8
    for (int h = 0; h < 512; ++h) acc = fmaf(q[h], wq[(size_t)h * Uv], acc);
    sTmp[half][u] = acc;
    if (tid < 128) P0[b * Uv + tid] = 0.0f;
    else           P1[b * Uv + (tid - 128)] = 0.0f;
    if (tid == 0) Ssg[b] = 0.0f;
    __syncthreads();
    if (tid < 128) pq[b * Uv + tid] = sTmp[0][tid] + sTmp[1][tid] + bq[tid];
  } else if (bx == 64) {
    // W2 (conv_w fold) -> bias2 -> w3tmp = W2@We -> pack W3F, all in one block
    __shared__ float sW2[31][128];
    __shared__ float sW3[32][128];
    if (tid < 128) {
      const int u = tid;
      float wl[32];
      #pragma unroll
      for (int f = 0; f < 32; ++f) wl[f] = Wl[f * Uv + u];
      for (int k = 0; k < 31; ++k) {
        float acc = 0.0f;
        #pragma unroll
        for (int f = 0; f < 32; ++f) acc = fmaf(conv_w[f * 31 + k], wl[f], acc);
        sW2[k][u] = acc;
      }
      float acc = bl[u];
      #pragma unroll
      for (int f = 0; f < 32; ++f) acc = fmaf(conv_b[f], wl[f], acc);
      bias2[u] = acc;
    }
    __syncthreads();
    if (tid < 128) {
      const int n = tid;
      for (int w = 0; w < 32; ++w) {
        float acc = 0.0f;
        if (w < 31) {
          for (int uu = 0; uu < Uv; ++uu)
            acc = fmaf(sW2[w][uu], We[(size_t)uu * Uv + n], acc);
        }
        sW3[w][n] = acc;
      }
    }
    __syncthreads();
    #pragma unroll
    for (int i = 0; i < 2; ++i) {
      const int idx = i * 256 + tid;            // 0..511
      const int nj = idx >> 6, lane = idx & 63;
      const int quad = lane >> 4, l4 = lane & 15;
      float v[8];
      #pragma unroll
      for (int j = 0; j < 8; ++j) v[j] = sW3[quad * 8 + j][nj * 16 + l4];
      uint4 o;
      o.x = pack2(f2bf(v[0]), f2bf(v[1]));
      o.y = pack2(f2bf(v[2]), f2bf(v[3]));
      o.z = pack2(f2bf(v[4]), f2bf(v[5]));
      o.w = pack2(f2bf(v[6]), f2bf(v[7]));
      *(uint4*)(W3F + (size_t)nj * 512 + lane * 8) = o;
    }
  } else {
    // Wm (fid<128) / We (128<=fid<160) fragment packing, 4 fids per block
    const int fid = (bx - 65) * 4 + (tid >> 6);
    const int lane = tid & 63;
    const int quad = lane >> 4, l4 = lane & 15;
    float v[8];
    unsigned short* dst;
    if (fid < 128) {
      const int kc = fid >> 3, uj = fid & 7;
      #pragma unroll
      for (int j = 0; j < 8; ++j) v[j] = Wm[(size_t)(kc * 32 + quad * 8 + j) * Uv + uj * 16 + l4];
      dst = WmF + (size_t)fid * 512 + lane * 8;
    } else {
      const int f2 = fid - 128;
      const int kc = f2 >> 3, nj = f2 & 7;
      #pragma unroll
      for (int j = 0; j < 8; ++j) v[j] = We[(size_t)(kc * 32 + quad * 8 + j) * Uv + nj * 16 + l4];
      dst = WeF + (size_t)f2 * 512 + lane * 8;
    }
    uint4 o;
    o.x = pack2(f2bf(v[0]), f2bf(v[1]));
    o.y = pack2(f2bf(v[2]), f2bf(v[3]));
    o.z = pack2(f2bf(v[4]), f2bf(v[5]));
    o.w = pack2(f2bf(v[6]), f2bf(v[7]));
    *(uint4*)dst = o;
  }
}

// ---------------- main fused kernel: pm GEMM (R1-proven staging) + energy/softmax + P0/P1 ----------------
// qe recomputed inline per block (hides under chunk-0 staging latency).
__global__ __launch_bounds__(256) void main_kernel(
    const float* __restrict__ memory, const unsigned short* __restrict__ WmF,
    const unsigned short* __restrict__ WeF, const unsigned short* __restrict__ W3F,
    const float* __restrict__ pq, const float* __restrict__ bias2,
    const float* __restrict__ be, const float* __restrict__ We,
    const float* __restrict__ state, const float* __restrict__ prev_cum,
    const float* __restrict__ bm, const float* __restrict__ va,
    float* __restrict__ P0, float* __restrict__ P1, float* __restrict__ Ssg) {
  const int tid = threadIdx.x;
  const int lane = tid & 63, wid = tid >> 6;
  const int l4 = lane & 15, quad = lane >> 4;
  const int wt = wid >> 1, wu = wid & 1;
  const int b = blockIdx.y, t0 = blockIdx.x * 64;

  __shared__ float sState[124];
  __shared__ float sPc[64];
  __shared__ float sBm[128];
  __shared__ float sVa[128];
  __shared__ float sSg[64];
  __shared__ float blkP0[128], blkP1[128];
  __shared__ float blkSsg;
  __shared__ float sQin[128];
  __shared__ float sQe[128];
  // sA[2][2048] f32 staging (16384 B) aliased with sS[64*144] bf16 (18432 B)
  __shared__ __align__(16) char smem[18432];
  float* sAf = (float*)smem;
  unsigned short* sS = (unsigned short*)smem;

  // staging source addresses: physical 16B slot p holds logical
  // (row = p>>3, c4 = (p&7) ^ (row&7)) -> inverse-swizzled source (R1-verified)
  const int p0 = tid, p1 = tid + 256;
  const int sr0 = p0 >> 3, sc0 = (p0 & 7) ^ (sr0 & 7);
  const int sr1 = p1 >> 3, sc1 = (p1 & 7) ^ (sr1 & 7);
  const float* g0 = memory + ((size_t)b * Tv + t0 + sr0) * Mv + sc0 * 4;
  const float* g1 = memory + ((size_t)b * Tv + t0 + sr1) * Mv + sc1 * 4;

  // prologue: stage chunk 0 into buffer 0 (earliest issue)
  {
    float* d = sAf + wid * 256;
    GLOAD_LDS16(g0, d); GLOAD_LDS16(g1, d + 1024);
  }

  // B-frag prologue (kc = 0)
  const unsigned short* bBase = WmF + (size_t)(wu * 4) * 512 + lane * 8;
  uint4 bc0 = *(const uint4*)(bBase);
  uint4 bc1 = *(const uint4*)(bBase + 512);
  uint4 bc2 = *(const uint4*)(bBase + 1024);
  uint4 bc3 = *(const uint4*)(bBase + 1536);

  // init small LDS
  for (int i = tid; i < 124; i += 256) {
    int t = t0 - 30 + i;
    sState[i] = (t >= 0 && t < Tv) ? state[b * Tv + t] : 0.0f;
  }
  if (tid < 64) sPc[tid] = prev_cum[b * Tv + t0 + tid];
  for (int i = tid; i < 128; i += 256) {
    float bmv = bm[i];
    sBm[i] = bmv; sVa[i] = va[i]; blkP0[i] = 0.0f; blkP1[i] = 0.0f;
    sQin[i] = pq[b * Uv + i] + bias2[i] + bmv;
  }
  if (tid == 0) blkSsg = 0.0f;

  // swizzled LDS read offsets (float4 units), chunk-invariant (R1-verified)
  const int r0 = wt * 32 + l4;
  const int q2 = quad * 2, rx = r0 & 7;
  const int s00 = r0 * 8 + (q2 ^ rx);
  const int s01 = r0 * 8 + ((q2 + 1) ^ rx);

  f32x4 acc[2][4];
  #pragma unroll
  for (int ti = 0; ti < 2; ++ti)
    #pragma unroll
    for (int uj = 0; uj < 4; ++uj) acc[ti][uj] = (f32x4){0.f, 0.f, 0.f, 0.f};

  __syncthreads();  // buffer 0 staged + inits (incl. sQin) visible

  // qe[n] = be[n] + sum_u sQin[u]*We[u][n] — runs while chunk 0/1 staging lands
  if (tid < 128) {
    float acc_q = be[tid];
    for (int u = 0; u < Uv; ++u) acc_q = fmaf(sQin[u], We[(size_t)u * Uv + tid], acc_q);
    sQe[tid] = acc_q;
  }

  // ---- phase 1: pm GEMM, 16 K-chunks of 32 (R1-proven loop)
  for (int kc = 0; kc < 16; ++kc) {
    const int cur = kc & 1;
    if (kc < 15) {
      float* d = sAf + (cur ? 0 : 2048) + wid * 256;
      GLOAD_LDS16(g0 + (kc + 1) * 32, d); GLOAD_LDS16(g1 + (kc + 1) * 32, d + 1024);
    }
    uint4 bn0, bn1, bn2, bn3;
    if (kc < 15) {
      const unsigned short* nb = bBase + (size_t)(kc + 1) * 4096;
      bn0 = *(const uint4*)(nb);
      bn1 = *(const uint4*)(nb + 512);
      bn2 = *(const uint4*)(nb + 1024);
      bn3 = *(const uint4*)(nb + 1536);
    }
    const float4* sf = (const float4*)(sAf) + (cur ? 512 : 0);
    float4 a0 = sf[s00];
    float4 a1 = sf[s01];
    float4 a2 = sf[s00 + 128];
    float4 a3 = sf[s01 + 128];
    bf16x8 af0, af1;
    af0[0] = (__bf16)a0.x; af0[1] = (__bf16)a0.y; af0[2] = (__bf16)a0.z; af0[3] = (__bf16)a0.w;
    af0[4] = (__bf16)a1.x; af0[5] = (__bf16)a1.y; af0[6] = (__bf16)a1.z; af0[7] = (__bf16)a1.w;
    af1[0] = (__bf16)a2.x; af1[1] = (__bf16)a2.y; af1[2] = (__bf16)a2.z; af1[3] = (__bf16)a2.w;
    af1[4] = (__bf16)a3.x; af1[5] = (__bf16)a3.y; af1[6] = (__bf16)a3.z; af1[7] = (__bf16)a3.w;
    U4BF u0, u1, u2, u3;
    u0.u = bc0; u1.u = bc1; u2.u = bc2; u3.u = bc3;
    acc[0][0] = MFMA(af0, u0.b, acc[0][0]);
    acc[1][0] = MFMA(af1, u0.b, acc[1][0]);
    acc[0][1] = MFMA(af0, u1.b, acc[0][1]);
    acc[1][1] = MFMA(af1, u1.b, acc[1][1]);
    acc[0][2] = MFMA(af0, u2.b, acc[0][2]);
    acc[1][2] = MFMA(af1, u2.b, acc[1][2]);
    acc[0][3] = MFMA(af0, u3.b, acc[0][3]);
    acc[1][3] = MFMA(af1, u3.b, acc[1][3]);
    if (kc < 15) {
      bc0 = bn0; bc1 = bn1; bc2 = bn2; bc3 = bn3;
      __syncthreads();
    }
  }

  __syncthreads();  // all waves done reading sA (aliased with sS)

  // write pm (bf16) to LDS; C layout: col=lane&15, row=quad*4+reg
  #pragma unroll
  for (int ti = 0; ti < 2; ++ti) {
    const int rowb = wt * 32 + ti * 16 + quad * 4;
    #pragma unroll
    for (int uj = 0; uj < 4; ++uj) {
      const int col = wu * 64 + uj * 16 + l4;
      #pragma unroll
      for (int r = 0; r < 4; ++r) sS[(rowb + r) * 144 + col] = f2bf(acc[ti][uj][r]);
    }
  }
  __syncthreads();

  // ---- phase 2: e2 = pm@We + S2@W3 + qe; wave wid owns rows wid*16..+16
  const int w = wid;
  f32x4 e[8];
  #pragma unroll
  for (int nj = 0; nj < 8; ++nj) {
    float qv = sQe[nj * 16 + l4];
    e[nj] = (f32x4){qv, qv, qv, qv};
  }
  bf16x8 a2f;
  #pragma unroll
  for (int j = 0; j < 8; ++j) {
    int k = quad * 8 + j;
    float v = (k < 31) ? sState[(w * 16 + l4) + 2 * k] : 0.0f;
    a2f[j] = (__bf16)v;
  }
  #pragma unroll
  for (int nj = 0; nj < 8; ++nj) {
    U4BF bb; bb.u = *(const uint4*)(W3F + (size_t)nj * 512 + lane * 8);
    e[nj] = MFMA(a2f, bb.b, e[nj]);
  }
  #pragma unroll
  for (int ks = 0; ks < 4; ++ks) {
    U4BF au;
    au.u = *(const uint4*)&sS[(w * 16 + l4) * 144 + ks * 32 + quad * 8];
    #pragma unroll
    for (int nj = 0; nj < 8; ++nj) {
      U4BF bb; bb.u = *(const uint4*)(WeF + (size_t)(ks * 8 + nj) * 512 + lane * 8);
      e[nj] = MFMA(au.b, bb.b, e[nj]);
    }
  }
  float p[4] = {0.f, 0.f, 0.f, 0.f};
  #pragma unroll
  for (int nj = 0; nj < 8; ++nj) {
    float vav = sVa[nj * 16 + l4];
    #pragma unroll
    for (int r = 0; r < 4; ++r) p[r] = fmaf(vav, tanh_fast(e[nj][r]), p[r]);
  }
  #pragma unroll
  for (int off = 1; off <= 8; off <<= 1) {
    #pragma unroll
    for (int r = 0; r < 4; ++r) p[r] += __shfl_xor(p[r], off, 64);
  }
  float sgv4[4], sgsum = 0.f;
  #pragma unroll
  for (int r = 0; r < 4; ++r) {
    sgv4[r] = sigmoid_fast(p[r]);
    sgsum += sgv4[r];
  }
  if (l4 == 0) {
    #pragma unroll
    for (int r = 0; r < 4; ++r) sSg[w * 16 + quad * 4 + r] = sgv4[r];
    atomicAdd(&blkSsg, sgsum);
  }
  __syncthreads();

  // ---- phase 3: P0/P1 accumulation from pm accumulators (register-resident)
  float sgl[8], pcl[8];
  #pragma unroll
  for (int ti = 0; ti < 2; ++ti)
    #pragma unroll
    for (int r = 0; r < 4; ++r) {
      int row = wt * 32 + ti * 16 + quad * 4 + r;
      sgl[ti * 4 + r] = sSg[row];
      pcl[ti * 4 + r] = sPc[row];
    }
  #pragma unroll
  for (int uj = 0; uj < 4; ++uj) {
    const int col = wu * 64 + uj * 16 + l4;
    const float bmv = sBm[col];
    float c0 = 0.f, c1 = 0.f;
    #pragma unroll
    for (int ti = 0; ti < 2; ++ti)
      #pragma unroll
      for (int r = 0; r < 4; ++r) {
        float pmv = acc[ti][uj][r] + bmv;
        c0 = fmaf(pcl[ti * 4 + r], pmv, c0);
        c1 = fmaf(sgl[ti * 4 + r], pmv, c1);
      }
    c0 += __shfl_xor(c0, 16, 64); c0 += __shfl_xor(c0, 32, 64);
    c1 += __shfl_xor(c1, 16, 64); c1 += __shfl_xor(c1, 32, 64);
    if (quad == 0) {
      atomicAdd(&blkP0[col], c0);
      atomicAdd(&blkP1[col], c1);
    }
  }
  __syncthreads();
  if (tid < 128) {
    unsafeAtomicAdd(&P0[b * Uv + tid], blkP0[tid]);
    unsafeAtomicAdd(&P1[b * Uv + tid], blkP1[tid]);
  }
  if (tid == 0) unsafeAtomicAdd(&Ssg[b], blkSsg);
}

// ---------------- finish: context = P0 + P1 / Ssg ----------------
__global__ __launch_bounds__(128) void finish_kernel(const float* __restrict__ P0,
                                                     const float* __restrict__ P1,
                                                     const float* __restrict__ Ssg,
                                                     float* __restrict__ out) {
  const int b = blockIdx.x, u = threadIdx.x;
  out[b * Uv + u] = P0[b * Uv + u] + P1[b * Uv + u] / Ssg[b];
}

extern "C" void kernel_launch(void* const* d_in, const int* in_sizes, int n_in,
                              void* d_out, int out_size, void* d_ws, size_t ws_size,
                              hipStream_t stream) {
  (void)in_sizes; (void)n_in; (void)out_size; (void)ws_size;
  const float* query    = (const float*)d_in[0];
  const float* state    = (const float*)d_in[1];
  const float* prev_cum = (const float*)d_in[2];
  const float* memory   = (const float*)d_in[3];
  const float* Wq       = (const float*)d_in[4];
  const float* bq       = (const float*)d_in[5];
  const float* Wm       = (const float*)d_in[6];
  const float* bm       = (const float*)d_in[7];
  const float* Wl       = (const float*)d_in[8];
  const float* bl       = (const float*)d_in[9];
  const float* We       = (const float*)d_in[10];
  const float* be       = (const float*)d_in[11];
  const float* va       = (const float*)d_in[12];
  const float* conv_w   = (const float*)d_in[13];
  const float* conv_b   = (const float*)d_in[14];

  float* ws = (float*)d_ws;
  float* P0    = ws;                 // 8192
  float* P1    = ws + 8192;          // 8192
  float* Ssg   = ws + 16384;         // 64
  float* pq    = ws + 16448;         // 8192
  float* bias2 = ws + 28608;         // 128
  unsigned short* WmF = (unsigned short*)(ws + 41024);  // 65536 bf16
  unsigned short* WeF = (unsigned short*)(ws + 73792);  // 16384 bf16
  unsigned short* W3F = (unsigned short*)(ws + 81984);  // 4096 bf16

  kpre_kernel<<<105, 256, 0, stream>>>(query, Wq, bq, Wl, bl, conv_w, conv_b, Wm, We,
                                       pq, bias2, WmF, WeF, W3F, P0, P1, Ssg);
  main_kernel<<<dim3(Tv / 64, Bv), 256, 0, stream>>>(
      memory, WmF, WeF, W3F, pq, bias2, be, We, state, prev_cum, bm, va, P0, P1, Ssg);
  finish_kernel<<<Bv, 128, 0, stream>>>(P0, P1, Ssg, (float*)d_out);
}

// Round 9
// 451.685 us; speedup vs baseline: 1.1321x; 1.1321x over previous
//
#include <hip/hip_runtime.h>

#define Bv 64
#define Tv 2048
#define Hv 1024
#define Uv 128
#define Mv 512

typedef __bf16 bf16x8 __attribute__((ext_vector_type(8)));
typedef float f32x4 __attribute__((ext_vector_type(4)));

union U4BF { uint4 u; bf16x8 b; };

#define MFMA(a, b, c) __builtin_amdgcn_mfma_f32_16x16x32_bf16((a), (b), (c), 0, 0, 0)

__device__ __forceinline__ unsigned short f2bf(float f) {
  __bf16 h = (__bf16)f;
  return __builtin_bit_cast(unsigned short, h);
}
__device__ __forceinline__ unsigned int pack2(unsigned short lo, unsigned short hi) {
  return (unsigned int)lo | ((unsigned int)hi << 16);
}
// fast tanh/sigmoid via v_exp (saturates correctly at +/-inf)
__device__ __forceinline__ float tanh_fast(float x) {
  float e = __expf(2.0f * x);
  return 1.0f - 2.0f / (e + 1.0f);
}
__device__ __forceinline__ float sigmoid_fast(float x) {
  return 1.0f / (1.0f + __expf(-x));
}

// ---------------- k1: pq[b,u] = query@Wq + bq  (bx<512)  |  W2/bias2 fold (bx==512) ----------------
__global__ __launch_bounds__(128) void k1_kernel(const float* __restrict__ query,
                                                 const float* __restrict__ Wq,
                                                 const float* __restrict__ bq,
                                                 const float* __restrict__ Wl,
                                                 const float* __restrict__ bl,
                                                 const float* __restrict__ conv_w,
                                                 const float* __restrict__ conv_b,
                                                 float* __restrict__ pq,
                                                 float* __restrict__ W2,
                                                 float* __restrict__ bias2) {
  const int bx = blockIdx.x;
  const int u = threadIdx.x;
  if (bx < 512) {
    const int b = bx >> 3, c = bx & 7;
    float acc = (c == 0) ? bq[u] : 0.0f;
    const float* q  = query + b * Hv + c * 128;
    const float* wq = Wq + (size_t)c * 128 * Uv;
    #pragma unroll 8
    for (int h = 0; h < 128; ++h) acc = fmaf(q[h], wq[h * Uv + u], acc);
    unsafeAtomicAdd(&pq[b * Uv + u], acc);
  } else {
    float wl[32];
    #pragma unroll
    for (int f = 0; f < 32; ++f) wl[f] = Wl[f * Uv + u];
    for (int k = 0; k < 31; ++k) {
      float acc = 0.0f;
      #pragma unroll
      for (int f = 0; f < 32; ++f) acc = fmaf(conv_w[f * 31 + k], wl[f], acc);
      W2[k * Uv + u] = acc;
    }
    float acc = bl[u];
    #pragma unroll
    for (int f = 0; f < 32; ++f) acc = fmaf(conv_b[f], wl[f], acc);
    bias2[u] = acc;
  }
}

// ---------------- k2: qe[b,n] = (pq[b]+bias2+bm)@We + be ;  w3tmp[k,n] = W2@We ----------------
__global__ __launch_bounds__(256) void k2_kernel(const float* __restrict__ pq,
                                                 const float* __restrict__ bias2,
                                                 const float* __restrict__ bm,
                                                 const float* __restrict__ be,
                                                 const float* __restrict__ We,
                                                 const float* __restrict__ W2,
                                                 float* __restrict__ qe,
                                                 float* __restrict__ w3tmp) {
  const int gtid = blockIdx.x * 256 + threadIdx.x;
  const int r = gtid >> 7, n = gtid & 127;
  if (r < 64) {
    float acc = be[n];
    for (int u = 0; u < Uv; ++u)
      acc = fmaf(pq[r * Uv + u] + bias2[u] + bm[u], We[u * Uv + n], acc);
    qe[r * Uv + n] = acc;
  } else {
    const int w = r - 64;
    float acc = 0.0f;
    if (w < 31) {
      for (int u = 0; u < Uv; ++u) acc = fmaf(W2[w * Uv + u], We[u * Uv + n], acc);
    }
    w3tmp[w * Uv + n] = acc;
  }
}

// ---------------- k3: pack Wm / We / w3tmp into bf16 MFMA B-fragment layout ----------------
__global__ __launch_bounds__(256) void k3_kernel(const float* __restrict__ Wm,
                                                 const float* __restrict__ We,
                                                 const float* __restrict__ w3tmp,
                                                 unsigned short* __restrict__ WmF,
                                                 unsigned short* __restrict__ WeF,
                                                 unsigned short* __restrict__ W3F) {
  const int gtid = blockIdx.x * 256 + threadIdx.x;
  const int fid = gtid >> 6, lane = gtid & 63;
  const int quad = lane >> 4, l4 = lane & 15;
  float v[8];
  unsigned short* dst;
  if (fid < 128) {                    // Wm: 16 kc x 8 uj
    const int kc = fid >> 3, uj = fid & 7;
    #pragma unroll
    for (int j = 0; j < 8; ++j) v[j] = Wm[(size_t)(kc * 32 + quad * 8 + j) * Uv + uj * 16 + l4];
    dst = WmF + (size_t)fid * 512 + lane * 8;
  } else if (fid < 160) {             // We: 4 kc x 8 nj
    const int f2 = fid - 128;
    const int kc = f2 >> 3, nj = f2 & 7;
    #pragma unroll
    for (int j = 0; j < 8; ++j) v[j] = We[(size_t)(kc * 32 + quad * 8 + j) * Uv + nj * 16 + l4];
    dst = WeF + (size_t)f2 * 512 + lane * 8;
  } else {                            // W3: 1 kc x 8 nj
    const int nj = fid - 160;
    #pragma unroll
    for (int j = 0; j < 8; ++j) v[j] = w3tmp[(quad * 8 + j) * Uv + nj * 16 + l4];
    dst = W3F + (size_t)nj * 512 + lane * 8;
  }
  uint4 o;
  o.x = pack2(f2bf(v[0]), f2bf(v[1]));
  o.y = pack2(f2bf(v[2]), f2bf(v[3]));
  o.z = pack2(f2bf(v[4]), f2bf(v[5]));
  o.w = pack2(f2bf(v[6]), f2bf(v[7]));
  *(uint4*)dst = o;
}

// ---------------- main fused kernel ----------------
// Phase 1: K processed in 4 quarters. Per quarter: preload that quarter's 16
// B-fragments into registers (64 VGPR, live all quarter -> compiler cannot
// sink them), then 4 chunks whose ONLY in-loop VMEM is the A-refill issued 4
// chunks ahead into static slots. The per-wave VMEM queue is monotone in
// consume-time: waiting A(kc) never drains newer prefetches; the single
// full-latency stall is one hiccup per quarter boundary. sched_barrier(0)
// (compile-time only, no HW op) pins issue order so the compiler cannot
// collapse the pipeline (R5's VGPR=80 proved it had). launch_bounds(256,2)
// grants the ~195-VGPR budget without spill.
__global__ __launch_bounds__(256, 2) void main_kernel(
    const float* __restrict__ memory, const unsigned short* __restrict__ WmF,
    const unsigned short* __restrict__ WeF, const unsigned short* __restrict__ W3F,
    const float* __restrict__ qe, const float* __restrict__ state,
    const float* __restrict__ prev_cum, const float* __restrict__ bm,
    const float* __restrict__ va,
    float* __restrict__ P0, float* __restrict__ P1, float* __restrict__ Ssg) {
  const int tid = threadIdx.x;
  const int lane = tid & 63, wid = tid >> 6;
  const int l4 = lane & 15, quad = lane >> 4;
  const int wt = wid >> 1, wu = wid & 1;
  const int b = blockIdx.y, t0 = blockIdx.x * 64;

  __shared__ float sState[124];
  __shared__ float sPc[64];
  __shared__ float sBm[128];
  __shared__ float sVa[128];
  __shared__ float sSg[64];
  __shared__ float blkP0[128], blkP1[128];
  __shared__ float blkSsg;
  __shared__ __align__(16) unsigned short sS[64 * 144];  // pm tile bf16, row stride 144

  const float* aBase = memory + ((size_t)b * Tv + t0 + wt * 32 + l4) * Mv + quad * 8;
  const unsigned short* bBase = WmF + (size_t)(wu * 4) * 512 + lane * 8;

  // ---- A pipeline prologue: 4 slots (chunks 0..3), issued before anything else
  float4 A0[4], A1[4], A2[4], A3[4];
  #pragma unroll
  for (int s = 0; s < 4; ++s) {
    const float* p = aBase + s * 32;
    A0[s] = *(const float4*)(p);
    A1[s] = *(const float4*)(p + 4);
    A2[s] = *(const float4*)(p + (size_t)16 * Mv);
    A3[s] = *(const float4*)(p + (size_t)16 * Mv + 4);
  }
  __builtin_amdgcn_sched_barrier(0);

  // ---- init small LDS (loads sit between A-prologue and B-preloads: harmless)
  for (int i = tid; i < 124; i += 256) {
    int t = t0 - 30 + i;
    sState[i] = (t >= 0 && t < Tv) ? state[b * Tv + t] : 0.0f;
  }
  if (tid < 64) sPc[tid] = prev_cum[b * Tv + t0 + tid];
  for (int i = tid; i < 128; i += 256) {
    sBm[i] = bm[i]; sVa[i] = va[i]; blkP0[i] = 0.0f; blkP1[i] = 0.0f;
  }
  if (tid == 0) blkSsg = 0.0f;

  f32x4 acc[2][4];
  #pragma unroll
  for (int ti = 0; ti < 2; ++ti)
    #pragma unroll
    for (int uj = 0; uj < 4; ++uj) acc[ti][uj] = (f32x4){0.f, 0.f, 0.f, 0.f};

  // ---- phase 1: 4 quarters x 4 chunks
  for (int q = 0; q < 4; ++q) {
    // quarter B-preload: 16 uint4, all live through the quarter
    uint4 Bq[4][4];
    #pragma unroll
    for (int kk = 0; kk < 4; ++kk) {
      const unsigned short* pb = bBase + (size_t)(q * 4 + kk) * 4096;
      Bq[kk][0] = *(const uint4*)(pb);
      Bq[kk][1] = *(const uint4*)(pb + 512);
      Bq[kk][2] = *(const uint4*)(pb + 1024);
      Bq[kk][3] = *(const uint4*)(pb + 1536);
    }
    __builtin_amdgcn_sched_barrier(0);
    #pragma unroll
    for (int kk = 0; kk < 4; ++kk) {
      const int kc = q * 4 + kk;
      // consume slot kk (static index)
      float4 a0 = A0[kk], a1 = A1[kk], a2 = A2[kk], a3 = A3[kk];
      bf16x8 af0, af1;
      af0[0] = (__bf16)a0.x; af0[1] = (__bf16)a0.y; af0[2] = (__bf16)a0.z; af0[3] = (__bf16)a0.w;
      af0[4] = (__bf16)a1.x; af0[5] = (__bf16)a1.y; af0[6] = (__bf16)a1.z; af0[7] = (__bf16)a1.w;
      af1[0] = (__bf16)a2.x; af1[1] = (__bf16)a2.y; af1[2] = (__bf16)a2.z; af1[3] = (__bf16)a2.w;
      af1[4] = (__bf16)a3.x; af1[5] = (__bf16)a3.y; af1[6] = (__bf16)a3.z; af1[7] = (__bf16)a3.w;
      U4BF u0, u1, u2, u3;
      u0.u = Bq[kk][0]; u1.u = Bq[kk][1]; u2.u = Bq[kk][2]; u3.u = Bq[kk][3];
      acc[0][0] = MFMA(af0, u0.b, acc[0][0]);
      acc[1][0] = MFMA(af1, u0.b, acc[1][0]);
      acc[0][1] = MFMA(af0, u1.b, acc[0][1]);
      acc[1][1] = MFMA(af1, u1.b, acc[1][1]);
      acc[0][2] = MFMA(af0, u2.b, acc[0][2]);
      acc[1][2] = MFMA(af1, u2.b, acc[1][2]);
      acc[0][3] = MFMA(af0, u3.b, acc[0][3]);
      acc[1][3] = MFMA(af1, u3.b, acc[1][3]);
      __builtin_amdgcn_sched_barrier(0);
      // refill slot kk with chunk kc+4 (issued ~3 chunks ahead of its use)
      if (q < 3) {
        const float* p = aBase + (size_t)(kc + 4) * 32;
        A0[kk] = *(const float4*)(p);
        A1[kk] = *(const float4*)(p + 4);
        A2[kk] = *(const float4*)(p + (size_t)16 * Mv);
        A3[kk] = *(const float4*)(p + (size_t)16 * Mv + 4);
      }
      __builtin_amdgcn_sched_barrier(0);
    }
  }

  // ---- write pm (bf16) to LDS; C layout: col=lane&15, row=quad*4+reg
  #pragma unroll
  for (int ti = 0; ti < 2; ++ti) {
    const int rowb = wt * 32 + ti * 16 + quad * 4;
    #pragma unroll
    for (int uj = 0; uj < 4; ++uj) {
      const int col = wu * 64 + uj * 16 + l4;
      #pragma unroll
      for (int r = 0; r < 4; ++r) sS[(rowb + r) * 144 + col] = f2bf(acc[ti][uj][r]);
    }
  }
  __syncthreads();

  // ---- phase 2: e2 = pm@We + S2@W3 + qe[b]; wave wid owns rows wid*16..+16
  const int w = wid;
  f32x4 e[8];
  #pragma unroll
  for (int nj = 0; nj < 8; ++nj) {
    float qv = qe[b * Uv + nj * 16 + l4];
    e[nj] = (f32x4){qv, qv, qv, qv};
  }
  bf16x8 a2f;
  #pragma unroll
  for (int j = 0; j < 8; ++j) {
    int k = quad * 8 + j;
    float v = (k < 31) ? sState[(w * 16 + l4) + 2 * k] : 0.0f;
    a2f[j] = (__bf16)v;
  }
  #pragma unroll
  for (int nj = 0; nj < 8; ++nj) {
    U4BF bb; bb.u = *(const uint4*)(W3F + (size_t)nj * 512 + lane * 8);
    e[nj] = MFMA(a2f, bb.b, e[nj]);
  }
  #pragma unroll
  for (int ks = 0; ks < 4; ++ks) {
    U4BF au;
    au.u = *(const uint4*)&sS[(w * 16 + l4) * 144 + ks * 32 + quad * 8];
    #pragma unroll
    for (int nj = 0; nj < 8; ++nj) {
      U4BF bb; bb.u = *(const uint4*)(WeF + (size_t)(ks * 8 + nj) * 512 + lane * 8);
      e[nj] = MFMA(au.b, bb.b, e[nj]);
    }
  }
  float p[4] = {0.f, 0.f, 0.f, 0.f};
  #pragma unroll
  for (int nj = 0; nj < 8; ++nj) {
    float vav = sVa[nj * 16 + l4];
    #pragma unroll
    for (int r = 0; r < 4; ++r) p[r] = fmaf(vav, tanh_fast(e[nj][r]), p[r]);
  }
  #pragma unroll
  for (int off = 1; off <= 8; off <<= 1) {
    #pragma unroll
    for (int r = 0; r < 4; ++r) p[r] += __shfl_xor(p[r], off, 64);
  }
  float sgv4[4], sgsum = 0.f;
  #pragma unroll
  for (int r = 0; r < 4; ++r) {
    sgv4[r] = sigmoid_fast(p[r]);
    sgsum += sgv4[r];
  }
  if (l4 == 0) {
    #pragma unroll
    for (int r = 0; r < 4; ++r) sSg[w * 16 + quad * 4 + r] = sgv4[r];
    atomicAdd(&blkSsg, sgsum);
  }
  __syncthreads();

  // ---- phase 3: P0/P1 accumulation from pm accumulators (register-resident)
  float sgl[8], pcl[8];
  #pragma unroll
  for (int ti = 0; ti < 2; ++ti)
    #pragma unroll
    for (int r = 0; r < 4; ++r) {
      int row = wt * 32 + ti * 16 + quad * 4 + r;
      sgl[ti * 4 + r] = sSg[row];
      pcl[ti * 4 + r] = sPc[row];
    }
  #pragma unroll
  for (int uj = 0; uj < 4; ++uj) {
    const int col = wu * 64 + uj * 16 + l4;
    const float bmv = sBm[col];
    float c0 = 0.f, c1 = 0.f;
    #pragma unroll
    for (int ti = 0; ti < 2; ++ti)
      #pragma unroll
      for (int r = 0; r < 4; ++r) {
        float pmv = acc[ti][uj][r] + bmv;
        c0 = fmaf(pcl[ti * 4 + r], pmv, c0);
        c1 = fmaf(sgl[ti * 4 + r], pmv, c1);
      }
    c0 += __shfl_xor(c0, 16, 64); c0 += __shfl_xor(c0, 32, 64);
    c1 += __shfl_xor(c1, 16, 64); c1 += __shfl_xor(c1, 32, 64);
    if (quad == 0) {
      atomicAdd(&blkP0[col], c0);
      atomicAdd(&blkP1[col], c1);
    }
  }
  __syncthreads();
  if (tid < 128) {
    unsafeAtomicAdd(&P0[b * Uv + tid], blkP0[tid]);
    unsafeAtomicAdd(&P1[b * Uv + tid], blkP1[tid]);
  }
  if (tid == 0) unsafeAtomicAdd(&Ssg[b], blkSsg);
}

// ---------------- finish: context = P0 + P1 / Ssg ----------------
__global__ __launch_bounds__(128) void finish_kernel(const float* __restrict__ P0,
                                                     const float* __restrict__ P1,
                                                     const float* __restrict__ Ssg,
                                                     float* __restrict__ out) {
  const int b = blockIdx.x, u = threadIdx.x;
  out[b * Uv + u] = P0[b * Uv + u] + P1[b * Uv + u] / Ssg[b];
}

extern "C" void kernel_launch(void* const* d_in, const int* in_sizes, int n_in,
                              void* d_out, int out_size, void* d_ws, size_t ws_size,
                              hipStream_t stream) {
  (void)in_sizes; (void)n_in; (void)out_size; (void)ws_size;
  const float* query    = (const float*)d_in[0];
  const float* state    = (const float*)d_in[1];
  const float* prev_cum = (const float*)d_in[2];
  const float* memory   = (const float*)d_in[3];
  const float* Wq       = (const float*)d_in[4];
  const float* bq       = (const float*)d_in[5];
  const float* Wm       = (const float*)d_in[6];
  const float* bm       = (const float*)d_in[7];
  const float* Wl       = (const float*)d_in[8];
  const float* bl       = (const float*)d_in[9];
  const float* We       = (const float*)d_in[10];
  const float* be       = (const float*)d_in[11];
  const float* va       = (const float*)d_in[12];
  const float* conv_w   = (const float*)d_in[13];
  const float* conv_b   = (const float*)d_in[14];

  float* ws = (float*)d_ws;
  float* P0    = ws;                 // 8192
  float* P1    = ws + 8192;          // 8192
  float* Ssg   = ws + 16384;         // 64
  float* pq    = ws + 16448;         // 8192
  float* W2    = ws + 24640;         // 3968
  float* bias2 = ws + 28608;         // 128
  float* qe    = ws + 28736;         // 8192
  float* w3tmp = ws + 36928;         // 4096 (32x128, row 31 zeroed)
  unsigned short* WmF = (unsigned short*)(ws + 41024);  // 65536 bf16
  unsigned short* WeF = (unsigned short*)(ws + 73792);  // 16384 bf16
  unsigned short* W3F = (unsigned short*)(ws + 81984);  // 4096 bf16

  hipMemsetAsync(d_ws, 0, 24640 * sizeof(float), stream);

  k1_kernel<<<513, 128, 0, stream>>>(query, Wq, bq, Wl, bl, conv_w, conv_b, pq, W2, bias2);
  k2_kernel<<<48, 256, 0, stream>>>(pq, bias2, bm, be, We, W2, qe, w3tmp);
  k3_kernel<<<42, 256, 0, stream>>>(Wm, We, w3tmp, WmF, WeF, W3F);
  main_kernel<<<dim3(Tv / 64, Bv), 256, 0, stream>>>(
      memory, WmF, WeF, W3F, qe, state, prev_cum, bm, va, P0, P1, Ssg);
  finish_kernel<<<Bv, 128, 0, stream>>>(P0, P1, Ssg, (float*)d_out);
}